// Round 1
// baseline (1137.473 us; speedup 1.0000x reference)
//
#include <hip/hip_runtime.h>
#include <hip/hip_bf16.h>
#include <cstdint>
#include <cstddef>

using bf16 = __hip_bfloat16;

typedef __attribute__((ext_vector_type(8))) short short8;   // bf16x8 MFMA A/B frag (4 VGPR)
typedef __attribute__((ext_vector_type(4))) float f32x4;    // MFMA C/D frag
typedef __attribute__((ext_vector_type(4))) unsigned short us4;

static constexpr int Bb = 4, Ss = 2048, Hh = 2048, Ii = 8192, Gg = 128;
static constexpr int Mm = Bb * Ss;   // 8192 tokens

// ---------------------------------------------------------------------------
// 1-bit group quantization: wq = sign(w) * mean(|w|) per contiguous 128-group.
// One wave per group: 64 lanes x float2.
// ---------------------------------------------------------------------------
__global__ void quant_onebit(const float* __restrict__ w, bf16* __restrict__ wq,
                             int ngroups) {
  int gid = blockIdx.x * 4 + (threadIdx.x >> 6);
  if (gid >= ngroups) return;
  int lane = threadIdx.x & 63;
  size_t base = (size_t)gid * Gg + (size_t)lane * 2;
  float2 v = *(const float2*)(w + base);
  float s = fabsf(v.x) + fabsf(v.y);
#pragma unroll
  for (int m = 32; m >= 1; m >>= 1) s += __shfl_xor(s, m);
  float scale = s * (1.0f / 128.0f);
  float q0 = (v.x > 0.f) ? scale : ((v.x < 0.f) ? -scale : 0.f);
  float q1 = (v.y > 0.f) ? scale : ((v.y < 0.f) ? -scale : 0.f);
  unsigned int p =
      (unsigned int)__builtin_bit_cast(unsigned short, __float2bfloat16(q0)) |
      ((unsigned int)__builtin_bit_cast(unsigned short, __float2bfloat16(q1)) << 16);
  *(unsigned int*)(wq + base) = p;
}

// ---------------------------------------------------------------------------
// f32 -> bf16 cast, 4 elems/thread
// ---------------------------------------------------------------------------
__global__ void cast_f32_bf16(const float* __restrict__ in, bf16* __restrict__ out,
                              size_t n4) {
  size_t i = (size_t)blockIdx.x * blockDim.x + threadIdx.x;
  if (i >= n4) return;
  float4 v = *(const float4*)(in + i * 4);
  us4 o;
  o.x = __builtin_bit_cast(unsigned short, __float2bfloat16(v.x));
  o.y = __builtin_bit_cast(unsigned short, __float2bfloat16(v.y));
  o.z = __builtin_bit_cast(unsigned short, __float2bfloat16(v.z));
  o.w = __builtin_bit_cast(unsigned short, __float2bfloat16(v.w));
  *(us4*)(out + i * 4) = o;
}

// ---------------------------------------------------------------------------
// B^T GEMM, 128x128 tile, BK=64, 4 waves, mfma_f32_16x16x32_bf16,
// global_load_lds width-16 staging (linear LDS layout = wave-uniform base).
// DUAL: two B matrices sharing the A tile; epilogue h = silu(g)*u -> bf16.
// !DUAL: single B; epilogue f32 store.
// All dims assumed divisible by 128 (true here).
// ---------------------------------------------------------------------------
__device__ __forceinline__ void gload16(const bf16* g, char* l) {
  __builtin_amdgcn_global_load_lds(
      (const __attribute__((address_space(1))) void*)g,
      (__attribute__((address_space(3))) void*)l, 16, 0, 0);
}

template <bool DUAL>
__global__ __launch_bounds__(256, 2)
void gemm_bt(const bf16* __restrict__ A,   // [M,K]
             const bf16* __restrict__ B0,  // [N,K]
             const bf16* __restrict__ B1,  // [N,K] (DUAL only)
             bf16* __restrict__ OutBf,     // [M,N] (DUAL only)
             float* __restrict__ OutF,     // [M,N] (!DUAL only)
             int M, int N, int K) {
  constexpr int BM = 128, BN = 128, BK = 64;
  __shared__ alignas(16) bf16 As[BM][BK];
  __shared__ alignas(16) bf16 Bs0[BN][BK];
  __shared__ alignas(16) bf16 Bs1[DUAL ? BN : 1][BK];

  const int tid = threadIdx.x;
  const int wid = tid >> 6;    // 0..3
  const int lane = tid & 63;

  // XCD-bijective block swizzle (nwg % 8 == 0 for all our grids)
  const int nbx = N / BN;
  const int nwg = (int)gridDim.x;
  const int cpx = nwg >> 3;
  const int wg = (int)blockIdx.x;
  const int swz = (wg & 7) * cpx + (wg >> 3);
  const int bm = swz / nbx;
  const int bn = swz % nbx;
  const int m0 = bm * BM;
  const int n0 = bn * BN;

  // wave -> 64x64 output quadrant
  const int wr = wid >> 1;  // 0..1
  const int wc = wid & 1;   // 0..1

  const f32x4 vzero = {0.f, 0.f, 0.f, 0.f};
  f32x4 acc0[4][4];
  f32x4 acc1[4][4];
#pragma unroll
  for (int m = 0; m < 4; ++m)
#pragma unroll
    for (int n = 0; n < 4; ++n) {
      acc0[m][n] = vzero;
      if constexpr (DUAL) acc1[m][n] = vzero;
    }

  // staging geometry: per call c, slot = c*4 + wid covers 8 rows (1024 B)
  const int srow = lane >> 3;        // 0..7
  const int scol = (lane & 7) * 8;   // bf16 elems, 16B per lane

  for (int k0 = 0; k0 < K; k0 += BK) {
#pragma unroll
    for (int c = 0; c < 4; ++c) {
      const int slot = c * 4 + wid;
      const int row = slot * 8 + srow;
      gload16(A + (size_t)(m0 + row) * K + k0 + scol,
              (char*)&As[0][0] + slot * 1024);
      gload16(B0 + (size_t)(n0 + row) * K + k0 + scol,
              (char*)&Bs0[0][0] + slot * 1024);
      if constexpr (DUAL)
        gload16(B1 + (size_t)(n0 + row) * K + k0 + scol,
                (char*)&Bs1[0][0] + slot * 1024);
    }
    __syncthreads();

#pragma unroll
    for (int kk = 0; kk < 2; ++kk) {
      const int ko = kk * 32 + (lane >> 4) * 8;
      short8 a[4], b0[4], b1[4];
#pragma unroll
      for (int m = 0; m < 4; ++m)
        a[m] = *(const short8*)&As[wr * 64 + m * 16 + (lane & 15)][ko];
#pragma unroll
      for (int n = 0; n < 4; ++n) {
        b0[n] = *(const short8*)&Bs0[wc * 64 + n * 16 + (lane & 15)][ko];
        if constexpr (DUAL)
          b1[n] = *(const short8*)&Bs1[wc * 64 + n * 16 + (lane & 15)][ko];
      }
#pragma unroll
      for (int m = 0; m < 4; ++m)
#pragma unroll
        for (int n = 0; n < 4; ++n) {
          acc0[m][n] = __builtin_amdgcn_mfma_f32_16x16x32_bf16(
              a[m], b0[n], acc0[m][n], 0, 0, 0);
          if constexpr (DUAL)
            acc1[m][n] = __builtin_amdgcn_mfma_f32_16x16x32_bf16(
                a[m], b1[n], acc1[m][n], 0, 0, 0);
        }
    }
    __syncthreads();
  }

  // epilogue: C/D layout col=lane&15, row=(lane>>4)*4 + j  [m89/m91 verified]
  const int crow0 = (lane >> 4) * 4;
  const int ccol = lane & 15;
#pragma unroll
  for (int m = 0; m < 4; ++m)
#pragma unroll
    for (int n = 0; n < 4; ++n)
#pragma unroll
      for (int j = 0; j < 4; ++j) {
        const int row = m0 + wr * 64 + m * 16 + crow0 + j;
        const int col = n0 + wc * 64 + n * 16 + ccol;
        if constexpr (DUAL) {
          float g = acc0[m][n][j];
          float u = acc1[m][n][j];
          float hv = (g / (1.0f + expf(-g))) * u;  // silu(g)*u
          OutBf[(size_t)row * N + col] = __float2bfloat16(hv);
        } else {
          OutF[(size_t)row * N + col] = acc0[m][n][j];
        }
      }
}

// ---------------------------------------------------------------------------
extern "C" void kernel_launch(void* const* d_in, const int* in_sizes, int n_in,
                              void* d_out, int out_size, void* d_ws, size_t ws_size,
                              hipStream_t stream) {
  const float* x = (const float*)d_in[0];
  const float* wg = (const float*)d_in[1];
  const float* wu = (const float*)d_in[2];
  const float* wd = (const float*)d_in[3];
  float* out = (float*)d_out;

  char* ws = (char*)d_ws;
  // layout (total 224 MiB):
  //   [0,32M)    xq  : x as bf16 [M,H]      -- reused later as wdq
  //   [32M,64M)  wgq : quantized w_gate bf16 [I,H]
  //   [64M,96M)  wuq : quantized w_up   bf16 [I,H]
  //   [96M,224M) hbuf: h bf16 [M,I]
  bf16* xq = (bf16*)(ws + 0);
  bf16* wgq = (bf16*)(ws + (size_t)33554432);
  bf16* wuq = (bf16*)(ws + (size_t)67108864);
  bf16* hbuf = (bf16*)(ws + (size_t)100663296);
  bf16* wdq = xq;  // wdq written after GEMM1 (xq dead by then)

  const int ngW = (Ii * Hh) / Gg;  // 131072 groups per weight
  quant_onebit<<<ngW / 4, 256, 0, stream>>>(wg, wgq, ngW);
  quant_onebit<<<ngW / 4, 256, 0, stream>>>(wu, wuq, ngW);

  const size_t n4 = (size_t)Mm * Hh / 4;
  cast_f32_bf16<<<(unsigned)((n4 + 255) / 256), 256, 0, stream>>>(x, xq, n4);

  // GEMM1 fused: gate/up = xq @ {wgq,wuq}^T ; h = silu(gate)*up -> bf16
  gemm_bt<true><<<(Mm / 128) * (Ii / 128), 256, 0, stream>>>(
      xq, wgq, wuq, hbuf, nullptr, Mm, Ii, Hh);

  quant_onebit<<<ngW / 4, 256, 0, stream>>>(wd, wdq, ngW);

  // GEMM2: out = h @ wdq^T  (f32 out)
  gemm_bt<false><<<(Mm / 128) * (Hh / 128), 256, 0, stream>>>(
      hbuf, wdq, nullptr, nullptr, out, Mm, Hh, Ii);
}

// Round 2
// 904.443 us; speedup vs baseline: 1.2577x; 1.2577x over previous
//
#include <hip/hip_runtime.h>
#include <hip/hip_bf16.h>
#include <cstdint>
#include <cstddef>

using bf16 = __hip_bfloat16;

typedef __attribute__((ext_vector_type(8))) short short8;   // bf16x8 MFMA A/B frag
typedef __attribute__((ext_vector_type(4))) float f32x4;    // MFMA C/D frag
typedef __attribute__((ext_vector_type(4))) unsigned short us4;

static constexpr int Bb = 4, Ss = 2048, Hh = 2048, Ii = 8192, Gg = 128;
static constexpr int Mm = Bb * Ss;   // 8192 tokens

#define MEMFENCE() asm volatile("" ::: "memory")
#define BARRIER() do { MEMFENCE(); __builtin_amdgcn_s_barrier(); MEMFENCE(); } while (0)

// ---------------------------------------------------------------------------
// 1-bit group quantization: wq = sign(w) * mean(|w|) per contiguous 128-group.
// ---------------------------------------------------------------------------
__global__ void quant_onebit(const float* __restrict__ w, bf16* __restrict__ wq,
                             int ngroups) {
  int gid = blockIdx.x * 4 + (threadIdx.x >> 6);
  if (gid >= ngroups) return;
  int lane = threadIdx.x & 63;
  size_t base = (size_t)gid * Gg + (size_t)lane * 2;
  float2 v = *(const float2*)(w + base);
  float s = fabsf(v.x) + fabsf(v.y);
#pragma unroll
  for (int m = 32; m >= 1; m >>= 1) s += __shfl_xor(s, m);
  float scale = s * (1.0f / 128.0f);
  float q0 = (v.x > 0.f) ? scale : ((v.x < 0.f) ? -scale : 0.f);
  float q1 = (v.y > 0.f) ? scale : ((v.y < 0.f) ? -scale : 0.f);
  unsigned int p =
      (unsigned int)__builtin_bit_cast(unsigned short, __float2bfloat16(q0)) |
      ((unsigned int)__builtin_bit_cast(unsigned short, __float2bfloat16(q1)) << 16);
  *(unsigned int*)(wq + base) = p;
}

__global__ void cast_f32_bf16(const float* __restrict__ in, bf16* __restrict__ out,
                              size_t n4) {
  size_t i = (size_t)blockIdx.x * blockDim.x + threadIdx.x;
  if (i >= n4) return;
  float4 v = *(const float4*)(in + i * 4);
  us4 o;
  o.x = __builtin_bit_cast(unsigned short, __float2bfloat16(v.x));
  o.y = __builtin_bit_cast(unsigned short, __float2bfloat16(v.y));
  o.z = __builtin_bit_cast(unsigned short, __float2bfloat16(v.z));
  o.w = __builtin_bit_cast(unsigned short, __float2bfloat16(v.w));
  *(us4*)(out + i * 4) = o;
}

// ---------------------------------------------------------------------------
// 8-wave 256-row GEMM, BK=32, 4-deep LDS ring, counted vmcnt, setprio,
// XOR slot-swizzle (both-sides). DUAL: fused gate/up + silu epilogue.
// ---------------------------------------------------------------------------
__device__ __forceinline__ void gload16(const bf16* g, char* l) {
  __builtin_amdgcn_global_load_lds(
      (const __attribute__((address_space(1))) void*)g,
      (__attribute__((address_space(3))) void*)l, 16, 0, 0);
}

// Read one MFMA frag from a swizzled LDS tile (rows of 32 bf16 = 64 B; the
// 16 B slot index is XORed with v(row) = (row ^ row>>2) & 3; 2-way max bank
// aliasing within each 16-lane group = free).
__device__ __forceinline__ short8 lds_frag(const char* tileBase, int row, int s) {
  int v = (row ^ (row >> 2)) & 3;
  return *(const short8*)(tileBase + row * 64 + (((s ^ v) & 3) << 4));
}

template <bool DUAL>
__global__ __launch_bounds__(512, 2)
void gemm_bt8(const bf16* __restrict__ A,   // [M,K]
              const bf16* __restrict__ B0,  // [N,K]
              const bf16* __restrict__ B1,  // [N,K] (DUAL)
              bf16* __restrict__ OutBf,     // [M,N] (DUAL)
              float* __restrict__ OutF,     // [M,N] (!DUAL)
              int M, int N, int K) {
  constexpr int BM = 256, BN = DUAL ? 128 : 256, BK = 32;
  constexpr int NF = DUAL ? 2 : 4;   // n-frags per wave
  constexpr int BUFB = 32768;        // bytes per ring slot: A 16K + B 16K
  extern __shared__ char smem[];     // 4 * 32768 = 128 KiB

  const int tid = threadIdx.x;
  const int wid = tid >> 6;          // 0..7
  const int lane = tid & 63;
  const int wr = wid >> 2;           // 0..1  (row half)
  const int wc = wid & 3;            // 0..3  (col quarter)
  const int lrow = lane & 15;
  const int s = lane >> 4;           // k-slot 0..3

  // XCD-bijective swizzle (all grids are multiples of 8)
  const int nbx = N / BN;
  const int nwg = (int)gridDim.x;
  const int cpx = nwg >> 3;
  const int wg = (int)blockIdx.x;
  const int swz = (wg & 7) * cpx + (wg >> 3);
  const int m0 = (swz / nbx) * BM;
  const int n0 = (swz % nbx) * BN;

  const int NT = K / BK;             // 64 (GEMM1) / 256 (GEMM2), both >= 3

  // ---- staging addressing: thread -> (row = tid>>2, slot = tid&3) of a
  // 128-row x 64B chunk; global source slot is inverse-swizzled so a linear
  // global_load_lds write + swizzled ds_read compose to identity.
  const int srow = tid >> 2;                         // 0..127
  const int sv = (srow ^ (srow >> 2)) & 3;
  const int scol = (((tid & 3) ^ sv) & 3) << 3;      // bf16 offset in row
  const bf16* pA0 = A + (size_t)(m0 + srow) * K + scol;
  const bf16* pA1 = A + (size_t)(m0 + 128 + srow) * K + scol;
  const bf16* pB0;
  const bf16* pB1;
  if constexpr (DUAL) {
    pB0 = B0 + (size_t)(n0 + srow) * K + scol;       // gate weights
    pB1 = B1 + (size_t)(n0 + srow) * K + scol;       // up weights
  } else {
    pB0 = B0 + (size_t)(n0 + srow) * K + scol;       // B rows 0..127
    pB1 = B0 + (size_t)(n0 + 128 + srow) * K + scol; // B rows 128..255
  }
  const int ldsOff = wid * 1024;     // wave-uniform base within a chunk

  auto stageA = [&](int u) {         // chunks c0,c1: A rows 0..255
    char* base = smem + (size_t)(u & 3) * BUFB;
    gload16(pA0 + u * BK, base + 0 + ldsOff);
    gload16(pA1 + u * BK, base + 8192 + ldsOff);
  };
  auto stageB = [&](int u) {         // chunks c2,c3: B panel(s)
    char* base = smem + (size_t)(u & 3) * BUFB;
    gload16(pB0 + u * BK, base + 16384 + ldsOff);
    gload16(pB1 + u * BK, base + 24576 + ldsOff);
  };

  const f32x4 vzero = {0.f, 0.f, 0.f, 0.f};
  f32x4 acc0[8][NF];
  f32x4 acc1[DUAL ? 8 : 1][NF];
#pragma unroll
  for (int mf = 0; mf < 8; ++mf)
#pragma unroll
    for (int nf = 0; nf < NF; ++nf) {
      acc0[mf][nf] = vzero;
      if constexpr (DUAL) acc1[mf][nf] = vzero;
    }

  // ---- prologue: stage tiles 0..2 (12 loads), wait tile0 (leave 8 in flight)
  stageA(0); stageB(0);
  stageA(1); stageB(1);
  stageA(2); stageB(2);
  asm volatile("s_waitcnt vmcnt(8)" ::: "memory");
  __builtin_amdgcn_s_barrier();
  MEMFENCE();

  short8 fb0[NF], fb1[DUAL ? NF : 1];

  for (int t = 0; t < NT; ++t) {
    const char* buf = smem + (size_t)(t & 3) * BUFB;
    const char* Ab = buf;            // [256][32] bf16
    const char* Bb = buf + 16384;    // [256][32] or B0[128][32]
    short8 fa[4];

    // ===== phase 0: frags (A mf 0..3 + all B) | stage t+3 A | barrier | MFMA
#pragma unroll
    for (int i = 0; i < 4; ++i)
      fa[i] = lds_frag(Ab, wr * 128 + i * 16 + lrow, s);
    if constexpr (DUAL) {
#pragma unroll
      for (int nf = 0; nf < 2; ++nf) {
        fb0[nf] = lds_frag(Bb, wc * 32 + nf * 16 + lrow, s);
        fb1[nf] = lds_frag(buf + 24576, wc * 32 + nf * 16 + lrow, s);
      }
    } else {
#pragma unroll
      for (int nf = 0; nf < 4; ++nf)
        fb0[nf] = lds_frag(Bb, wc * 64 + nf * 16 + lrow, s);
    }
    if (t + 3 < NT) stageA(t + 3);
    BARRIER();
    __builtin_amdgcn_s_setprio(1);
#pragma unroll
    for (int i = 0; i < 4; ++i)
#pragma unroll
      for (int nf = 0; nf < NF; ++nf) {
        acc0[i][nf] = __builtin_amdgcn_mfma_f32_16x16x32_bf16(
            fa[i], fb0[nf], acc0[i][nf], 0, 0, 0);
        if constexpr (DUAL)
          acc1[i][nf] = __builtin_amdgcn_mfma_f32_16x16x32_bf16(
              fa[i], fb1[nf], acc1[i][nf], 0, 0, 0);
      }
    __builtin_amdgcn_s_setprio(0);
    BARRIER();

    // ===== phase 1: frags (A mf 4..7; B reused) | stage t+3 B | barrier | MFMA
#pragma unroll
    for (int i = 0; i < 4; ++i)
      fa[i] = lds_frag(Ab, wr * 128 + (4 + i) * 16 + lrow, s);
    if (t + 3 < NT) stageB(t + 3);
    BARRIER();
    __builtin_amdgcn_s_setprio(1);
#pragma unroll
    for (int i = 0; i < 4; ++i)
#pragma unroll
      for (int nf = 0; nf < NF; ++nf) {
        acc0[4 + i][nf] = __builtin_amdgcn_mfma_f32_16x16x32_bf16(
            fa[i], fb0[nf], acc0[4 + i][nf], 0, 0, 0);
        if constexpr (DUAL)
          acc1[4 + i][nf] = __builtin_amdgcn_mfma_f32_16x16x32_bf16(
              fa[i], fb1[nf], acc1[4 + i][nf], 0, 0, 0);
      }
    __builtin_amdgcn_s_setprio(0);

    // ===== group end: ensure tile t+1 landed (counted — never drain mid-loop)
    const int r = NT - 1 - t;
    MEMFENCE();
    if (r >= 3)      asm volatile("s_waitcnt vmcnt(8)" ::: "memory");
    else if (r == 2) asm volatile("s_waitcnt vmcnt(4)" ::: "memory");
    else if (r == 1) asm volatile("s_waitcnt vmcnt(0)" ::: "memory");
    __builtin_amdgcn_s_barrier();
    MEMFENCE();
  }

  // ---- epilogue: C/D layout col=lane&15, row=(lane>>4)*4+j
  const int crow0 = (lane >> 4) * 4;
  const int ccol = lane & 15;
#pragma unroll
  for (int mf = 0; mf < 8; ++mf)
#pragma unroll
    for (int nf = 0; nf < NF; ++nf)
#pragma unroll
      for (int j = 0; j < 4; ++j) {
        const int row = m0 + wr * 128 + mf * 16 + crow0 + j;
        if constexpr (DUAL) {
          const int col = n0 + wc * 32 + nf * 16 + ccol;
          float g = acc0[mf][nf][j];
          float u = acc1[mf][nf][j];
          OutBf[(size_t)row * N + col] =
              __float2bfloat16(g / (1.0f + expf(-g)) * u);
        } else {
          const int col = n0 + wc * 64 + nf * 16 + ccol;
          OutF[(size_t)row * N + col] = acc0[mf][nf][j];
        }
      }
}

// ---------------------------------------------------------------------------
extern "C" void kernel_launch(void* const* d_in, const int* in_sizes, int n_in,
                              void* d_out, int out_size, void* d_ws, size_t ws_size,
                              hipStream_t stream) {
  const float* x = (const float*)d_in[0];
  const float* wg = (const float*)d_in[1];
  const float* wu = (const float*)d_in[2];
  const float* wd = (const float*)d_in[3];
  float* out = (float*)d_out;

  char* ws = (char*)d_ws;
  bf16* xq = (bf16*)(ws + 0);
  bf16* wgq = (bf16*)(ws + (size_t)33554432);
  bf16* wuq = (bf16*)(ws + (size_t)67108864);
  bf16* hbuf = (bf16*)(ws + (size_t)100663296);
  bf16* wdq = xq;  // xq dead after GEMM1

  // 128 KiB dynamic LDS needs the attribute; host-side, idempotent,
  // graph-capture-safe (not a stream op), persists for replays.
  auto* kDual = gemm_bt8<true>;
  auto* kSingle = gemm_bt8<false>;
  (void)hipFuncSetAttribute((const void*)kDual,
                            hipFuncAttributeMaxDynamicSharedMemorySize, 131072);
  (void)hipFuncSetAttribute((const void*)kSingle,
                            hipFuncAttributeMaxDynamicSharedMemorySize, 131072);

  const int ngW = (Ii * Hh) / Gg;
  quant_onebit<<<ngW / 4, 256, 0, stream>>>(wg, wgq, ngW);
  quant_onebit<<<ngW / 4, 256, 0, stream>>>(wu, wuq, ngW);

  const size_t n4 = (size_t)Mm * Hh / 4;
  cast_f32_bf16<<<(unsigned)((n4 + 255) / 256), 256, 0, stream>>>(x, xq, n4);

  // GEMM1 fused: h = silu(x@wgq^T) * (x@wuq^T)  [M=8192, N=8192, K=2048]
  kDual<<<(Mm / 256) * (Ii / 128), 512, 131072, stream>>>(
      xq, wgq, wuq, hbuf, nullptr, Mm, Ii, Hh);

  quant_onebit<<<ngW / 4, 256, 0, stream>>>(wd, wdq, ngW);

  // GEMM2: out = h @ wdq^T  [M=8192, N=2048, K=8192]
  kSingle<<<(Mm / 256) * (Hh / 256), 512, 131072, stream>>>(
      hbuf, wdq, nullptr, nullptr, out, Mm, Hh, Ii);
}

// Round 3
// 842.890 us; speedup vs baseline: 1.3495x; 1.0730x over previous
//
#include <hip/hip_runtime.h>
#include <hip/hip_bf16.h>
#include <cstdint>
#include <cstddef>

using bf16 = __hip_bfloat16;

typedef __attribute__((ext_vector_type(8))) short short8;   // bf16x8 MFMA A/B frag
typedef __attribute__((ext_vector_type(4))) float f32x4;    // MFMA C/D frag
typedef __attribute__((ext_vector_type(4))) unsigned short us4;

static constexpr int Bb = 4, Ss = 2048, Hh = 2048, Ii = 8192, Gg = 128;
static constexpr int Mm = Bb * Ss;   // 8192 tokens

#define MEMFENCE() asm volatile("" ::: "memory")
#define BARRIER() do { MEMFENCE(); __builtin_amdgcn_s_barrier(); MEMFENCE(); } while (0)

// ---------------------------------------------------------------------------
// 1-bit group quantization: wq = sign(w) * mean(|w|) per contiguous 128-group.
// ---------------------------------------------------------------------------
__global__ void quant_onebit(const float* __restrict__ w, bf16* __restrict__ wq,
                             int ngroups) {
  int gid = blockIdx.x * 4 + (threadIdx.x >> 6);
  if (gid >= ngroups) return;
  int lane = threadIdx.x & 63;
  size_t base = (size_t)gid * Gg + (size_t)lane * 2;
  float2 v = *(const float2*)(w + base);
  float s = fabsf(v.x) + fabsf(v.y);
#pragma unroll
  for (int m = 32; m >= 1; m >>= 1) s += __shfl_xor(s, m);
  float scale = s * (1.0f / 128.0f);
  float q0 = (v.x > 0.f) ? scale : ((v.x < 0.f) ? -scale : 0.f);
  float q1 = (v.y > 0.f) ? scale : ((v.y < 0.f) ? -scale : 0.f);
  unsigned int p =
      (unsigned int)__builtin_bit_cast(unsigned short, __float2bfloat16(q0)) |
      ((unsigned int)__builtin_bit_cast(unsigned short, __float2bfloat16(q1)) << 16);
  *(unsigned int*)(wq + base) = p;
}

__global__ void cast_f32_bf16(const float* __restrict__ in, bf16* __restrict__ out,
                              size_t n4) {
  size_t i = (size_t)blockIdx.x * blockDim.x + threadIdx.x;
  if (i >= n4) return;
  float4 v = *(const float4*)(in + i * 4);
  us4 o;
  o.x = __builtin_bit_cast(unsigned short, __float2bfloat16(v.x));
  o.y = __builtin_bit_cast(unsigned short, __float2bfloat16(v.y));
  o.z = __builtin_bit_cast(unsigned short, __float2bfloat16(v.z));
  o.w = __builtin_bit_cast(unsigned short, __float2bfloat16(v.w));
  *(us4*)(out + i * 4) = o;
}

// ---------------------------------------------------------------------------
// 256-row GEMM, BK=64, 2-deep dbuf, 4 phases/tile, K-slice staged with a
// uniform counted vmcnt(4); full XOR slot-swizzle (2-way max = free).
// DUAL: fused gate/up (two 128-col B panels) + silu epilogue -> bf16.
// ---------------------------------------------------------------------------
__device__ __forceinline__ void gload16(const bf16* g, char* l) {
  __builtin_amdgcn_global_load_lds(
      (const __attribute__((address_space(1))) void*)g,
      (__attribute__((address_space(3))) void*)l, 16, 0, 0);
}

// Swizzled frag read: row stride 64 B (4 x 16 B slots), phys slot = s ^ (row>>1)&3.
// 16-lane group (same s, 16 consecutive rows) -> 8 distinct bank-starts x2 = free.
__device__ __forceinline__ short8 lfrag(const char* part, int row, int s) {
  return *(const short8*)(part + row * 64 + (((s ^ (row >> 1)) & 3) << 4));
}

template <bool DUAL>
__global__ __launch_bounds__(512, 2)
void gemm_bt8(const bf16* __restrict__ A,   // [M,K]
              const bf16* __restrict__ B0,  // [N,K]
              const bf16* __restrict__ B1,  // [N,K] (DUAL)
              bf16* __restrict__ OutBf,     // [M,N] (DUAL)
              float* __restrict__ OutF,     // [M,N] (!DUAL)
              int M, int N, int K) {
  constexpr int BM = 256, BN = DUAL ? 128 : 256;
  constexpr int NF = DUAL ? 2 : 4;        // n-frags per wave (per matrix)
  // LDS: buf[2] x slice[2] x (A 16K + B 16K) = 131072 B
  extern __shared__ char smem[];

  const int tid = threadIdx.x;
  const int wid = tid >> 6;               // 0..7
  const int lane = tid & 63;
  const int wr = wid >> 2;                // 0..1 row half
  const int wc = wid & 3;                 // 0..3 col quarter
  const int lrow = lane & 15;
  const int ks = lane >> 4;               // 16B slot 0..3 within 64B k-slice row

  // XCD-bijective swizzle (grids are multiples of 8)
  const int nbx = N / BN;
  const int nwg = (int)gridDim.x;
  const int cpx = nwg >> 3;
  const int wg = (int)blockIdx.x;
  const int swz = (wg & 7) * cpx + (wg >> 3);
  const int m0 = (swz / nbx) * BM;
  const int n0 = (swz % nbx) * BN;

  const int NT = K / 64;

  // ---- staging: dest is linear (unit = c*512 + tid -> byte = unit*16);
  // source slot inverse-swizzled: s_log = (tid&3) ^ ((tid>>3)&3) (same for all
  // 128-row sub-regions since region row offsets are multiples of 128).
  const int srow = tid >> 2;                          // 0..127
  const int slog8 = (((tid & 3) ^ ((tid >> 3) & 3)) << 3);  // elem offset in slice
  const bf16* pA0 = A + (size_t)(m0 + srow) * K + slog8;
  const bf16* pA1 = pA0 + (size_t)128 * K;
  const bf16* pB0 = B0 + (size_t)(n0 + srow) * K + slog8;
  const bf16* pB1 = DUAL ? (B1 + (size_t)(n0 + srow) * K + slog8)
                         : (pB0 + (size_t)128 * K);
  const int dA = wid * 1024;              // wave-uniform dest base (lane*16 auto)

  auto stageA = [&](int t, int p) {       // A slice: rows 0..255 x 32 elems
    char* b = smem + (size_t)(t & 1) * 65536 + p * 32768;
    const int koff = t * 64 + p * 32;
    gload16(pA0 + koff, b + dA);
    gload16(pA1 + koff, b + 8192 + dA);
  };
  auto stageB = [&](int t, int p) {       // B slice (both panels / both halves)
    char* b = smem + (size_t)(t & 1) * 65536 + p * 32768 + 16384;
    const int koff = t * 64 + p * 32;
    gload16(pB0 + koff, b + dA);
    gload16(pB1 + koff, b + 8192 + dA);
  };

  const f32x4 vzero = {0.f, 0.f, 0.f, 0.f};
  f32x4 acc0[8][NF];
  f32x4 acc1[DUAL ? 8 : 1][NF];
#pragma unroll
  for (int mf = 0; mf < 8; ++mf)
#pragma unroll
    for (int nf = 0; nf < NF; ++nf) {
      acc0[mf][nf] = vzero;
      if constexpr (DUAL) acc1[mf][nf] = vzero;
    }

  // ---- prologue: stage tile0 fully (8 loads; order s0A,s0B,s1A,s1B)
  stageA(0, 0); stageB(0, 0);
  stageA(0, 1); stageB(0, 1);

  short8 fa[4], fb0[NF], fb1[DUAL ? NF : 1];

  for (int t = 0; t < NT; ++t) {
    const char* buf = smem + (size_t)(t & 1) * 65536;
#pragma unroll
    for (int p = 0; p < 2; ++p) {
      const char* Ap = buf + p * 32768;
      const char* Bp = Ap + 16384;

      // ===== phase (p,0): wait slice p, read B + A[mf0-3], stage A(t+1,p)
      if (p == 0 || t + 1 < NT)
        asm volatile("s_waitcnt vmcnt(4)" ::: "memory");
      else
        asm volatile("s_waitcnt vmcnt(0)" ::: "memory");
      BARRIER();
      if constexpr (DUAL) {
#pragma unroll
        for (int nf = 0; nf < 2; ++nf) {
          fb0[nf] = lfrag(Bp, wc * 32 + nf * 16 + lrow, ks);
          fb1[nf] = lfrag(Bp + 8192, wc * 32 + nf * 16 + lrow, ks);
        }
      } else {
#pragma unroll
        for (int nf = 0; nf < 4; ++nf)
          fb0[nf] = lfrag(Bp, wc * 64 + nf * 16 + lrow, ks);
      }
#pragma unroll
      for (int i = 0; i < 4; ++i)
        fa[i] = lfrag(Ap, wr * 128 + i * 16 + lrow, ks);
      if (t + 1 < NT) stageA(t + 1, p);
      __builtin_amdgcn_s_setprio(1);
#pragma unroll
      for (int i = 0; i < 4; ++i)
#pragma unroll
        for (int nf = 0; nf < NF; ++nf) {
          acc0[i][nf] = __builtin_amdgcn_mfma_f32_16x16x32_bf16(
              fa[i], fb0[nf], acc0[i][nf], 0, 0, 0);
          if constexpr (DUAL)
            acc1[i][nf] = __builtin_amdgcn_mfma_f32_16x16x32_bf16(
                fa[i], fb1[nf], acc1[i][nf], 0, 0, 0);
        }
      __builtin_amdgcn_s_setprio(0);
      BARRIER();

      // ===== phase (p,1): read A[mf4-7] (B reused), stage B(t+1,p)
#pragma unroll
      for (int i = 0; i < 4; ++i)
        fa[i] = lfrag(Ap, wr * 128 + 64 + i * 16 + lrow, ks);
      if (t + 1 < NT) stageB(t + 1, p);
      __builtin_amdgcn_s_setprio(1);
#pragma unroll
      for (int i = 0; i < 4; ++i)
#pragma unroll
        for (int nf = 0; nf < NF; ++nf) {
          acc0[4 + i][nf] = __builtin_amdgcn_mfma_f32_16x16x32_bf16(
              fa[i], fb0[nf], acc0[4 + i][nf], 0, 0, 0);
          if constexpr (DUAL)
            acc1[4 + i][nf] = __builtin_amdgcn_mfma_f32_16x16x32_bf16(
                fa[i], fb1[nf], acc1[4 + i][nf], 0, 0, 0);
        }
      __builtin_amdgcn_s_setprio(0);
    }
  }

  // ---- epilogue: C/D layout col=lane&15, row=(lane>>4)*4+j
  const int crow0 = (lane >> 4) * 4;
  const int ccol = lane & 15;
#pragma unroll
  for (int mf = 0; mf < 8; ++mf)
#pragma unroll
    for (int nf = 0; nf < NF; ++nf)
#pragma unroll
      for (int j = 0; j < 4; ++j) {
        const int row = m0 + wr * 128 + mf * 16 + crow0 + j;
        if constexpr (DUAL) {
          const int col = n0 + wc * 32 + nf * 16 + ccol;
          float g = acc0[mf][nf][j];
          float u = acc1[mf][nf][j];
          OutBf[(size_t)row * N + col] =
              __float2bfloat16(g / (1.0f + expf(-g)) * u);
        } else {
          const int col = n0 + wc * 64 + nf * 16 + ccol;
          OutF[(size_t)row * N + col] = acc0[mf][nf][j];
        }
      }
}

// ---------------------------------------------------------------------------
extern "C" void kernel_launch(void* const* d_in, const int* in_sizes, int n_in,
                              void* d_out, int out_size, void* d_ws, size_t ws_size,
                              hipStream_t stream) {
  const float* x = (const float*)d_in[0];
  const float* wg = (const float*)d_in[1];
  const float* wu = (const float*)d_in[2];
  const float* wd = (const float*)d_in[3];
  float* out = (float*)d_out;

  char* ws = (char*)d_ws;
  bf16* xq = (bf16*)(ws + 0);
  bf16* wgq = (bf16*)(ws + (size_t)33554432);
  bf16* wuq = (bf16*)(ws + (size_t)67108864);
  bf16* hbuf = (bf16*)(ws + (size_t)100663296);
  bf16* wdq = xq;  // xq dead after GEMM1

  auto* kDual = gemm_bt8<true>;
  auto* kSingle = gemm_bt8<false>;
  (void)hipFuncSetAttribute((const void*)kDual,
                            hipFuncAttributeMaxDynamicSharedMemorySize, 131072);
  (void)hipFuncSetAttribute((const void*)kSingle,
                            hipFuncAttributeMaxDynamicSharedMemorySize, 131072);

  const int ngW = (Ii * Hh) / Gg;
  quant_onebit<<<ngW / 4, 256, 0, stream>>>(wg, wgq, ngW);
  quant_onebit<<<ngW / 4, 256, 0, stream>>>(wu, wuq, ngW);

  const size_t n4 = (size_t)Mm * Hh / 4;
  cast_f32_bf16<<<(unsigned)((n4 + 255) / 256), 256, 0, stream>>>(x, xq, n4);

  // GEMM1 fused: h = silu(x@wgq^T) * (x@wuq^T)  [M=8192, N=8192, K=2048]
  kDual<<<(Mm / 256) * (Ii / 128), 512, 131072, stream>>>(
      xq, wgq, wuq, hbuf, nullptr, Mm, Ii, Hh);

  quant_onebit<<<ngW / 4, 256, 0, stream>>>(wd, wdq, ngW);

  // GEMM2: out = h @ wdq^T  [M=8192, N=2048, K=8192]
  kSingle<<<(Mm / 256) * (Hh / 256), 512, 131072, stream>>>(
      hbuf, wdq, nullptr, nullptr, out, Mm, Hh, Ii);
}